// Round 1
// baseline (247.279 us; speedup 1.0000x reference)
//
#include <hip/hip_runtime.h>

// MAMBA chunk scan: out[b,c,m,h,p] =
//   exp(dA[m]) * ( sum_n C[b,c,m,n]*prev[b,c,h,p,n]
//                + sum_{k<=m} cb[b,c,m,k]*exp(-dA[k])*dt[k]*x[b,c,k,h,p]
//                + (diag) D[h]*exp(-dA[m])*x[b,c,m,h,p] )
// One block per (b,c,h): fused K=384 bf16 MFMA GEMM, M=256, N(p)=64.
// B=2 S=4096 CS=256 H=32 G=1 P=64 N=128 NC=16

typedef unsigned short u16;
typedef __bf16 v8bf __attribute__((ext_vector_type(8)));
typedef unsigned short v8u16 __attribute__((ext_vector_type(8)));
typedef float v4f __attribute__((ext_vector_type(4)));

#define LDA 40  // LDS row stride (bf16 elems): 80B = 20 banks, 16B aligned
#define LDB 40

__device__ __forceinline__ u16 f2bf(float f) {
  unsigned u = __builtin_bit_cast(unsigned, f);
  unsigned r = u + 0x7FFFu + ((u >> 16) & 1u);  // RNE
  return (u16)(r >> 16);
}

__global__ __launch_bounds__(256) void mamba_cs_kernel(
    const float* __restrict__ cbp,   // (2,16,1,256,256)
    const float* __restrict__ xp,    // (2,4096,32,64)
    const float* __restrict__ dtp,   // (2,32,16,256)
    const float* __restrict__ dAp,   // (2,32,16,256)
    const float* __restrict__ Cp,    // (2,4096,1,128)
    const float* __restrict__ pvp,   // (2,16,32,64,128)
    const float* __restrict__ Dp,    // (32,)
    float* __restrict__ outp)        // (2,4096,32,64)
{
  __shared__ u16 sA[256 * LDA];
  __shared__ u16 sB[64 * LDB];
  __shared__ float s_edm[256];   // exp(dA[m])
  __shared__ float s_w[256];     // exp(-dA[k]) * dt[k]
  __shared__ float s_winv[256];  // exp(-dA[m])

  const int bid = blockIdx.x;
  const int h = bid & 31;
  const int c = (bid >> 5) & 15;
  const int b = bid >> 9;
  const int t = threadIdx.x;
  const int lane = t & 63;
  const int wid = t >> 6;

  // ---- prologue: decay factors ----
  {
    const int base = ((b * 32 + h) * 16 + c) * 256 + t;
    float dAv = dAp[base];
    float dtv = dtp[base];
    s_edm[t] = __expf(dAv);
    float wi = __expf(-dAv);
    s_winv[t] = wi;
    s_w[t] = wi * dtv;
  }
  const float Dh = Dp[h];

  v4f acc[4][4];
#pragma unroll
  for (int i = 0; i < 4; i++)
#pragma unroll
    for (int j = 0; j < 4; j++) acc[i][j] = (v4f){0.f, 0.f, 0.f, 0.f};

  const float* Cbase = Cp + (size_t)(b * 4096 + c * 256) * 128;
  const float* Pbase = pvp + (size_t)((b * 16 + c) * 32 + h) * 64 * 128;
  const float* CBbase = cbp + (size_t)(b * 16 + c) * 65536;
  const float* Xbase = xp + ((size_t)(b * 4096 + c * 256) * 32 + h) * 64;  // row stride 2048

  __syncthreads();  // s_w/s_winv ready

  for (int kt = 0; kt < 12; ++kt) {
    // ---------- stage tiles into LDS (fp32 -> bf16) ----------
    if (kt < 4) {
      const int n0 = kt * 32;
      // A[m][k=n-n0] = C[m][n]  (256x32)
#pragma unroll
      for (int i = 0; i < 8; i++) {
        int v = t + i * 256;       // float4 index 0..2047
        int m = v >> 3;
        int co = (v & 7) * 4;
        const float4 f = *(const float4*)(Cbase + (size_t)m * 128 + n0 + co);
        u16* dst = &sA[m * LDA + co];
        dst[0] = f2bf(f.x); dst[1] = f2bf(f.y); dst[2] = f2bf(f.z); dst[3] = f2bf(f.w);
      }
      // B stored transposed: sB[p][k=n-n0] = prev[p][n]  (64x32)
#pragma unroll
      for (int i = 0; i < 2; i++) {
        int v = t + i * 256;       // float4 index 0..511
        int p = v >> 3;
        int no = (v & 7) * 4;
        const float4 f = *(const float4*)(Pbase + (size_t)p * 128 + n0 + no);
        u16* dst = &sB[p * LDB + no];
        dst[0] = f2bf(f.x); dst[1] = f2bf(f.y); dst[2] = f2bf(f.z); dst[3] = f2bf(f.w);
      }
    } else {
      const int k0 = (kt - 4) * 32;
      // A[m][k-k0] = mask(k<=m) * cb[m][k]*w[k]  (+ D*winv on diagonal)
#pragma unroll
      for (int i = 0; i < 8; i++) {
        int v = t + i * 256;
        int m = v >> 3;
        int ko = (v & 7) * 4;
        const float4 f = *(const float4*)(CBbase + (size_t)m * 256 + k0 + ko);
        float vals[4] = {f.x, f.y, f.z, f.w};
        u16* dst = &sA[m * LDA + ko];
#pragma unroll
        for (int j = 0; j < 4; j++) {
          int k = k0 + ko + j;
          float val = (k <= m) ? vals[j] * s_w[k] : 0.f;
          if (k == m) val += Dh * s_winv[m];
          dst[j] = f2bf(val);
        }
      }
      // B transposed: sB[p][k-k0] = x[k][p]; pack 2 k's per u32 write.
      // p = pg + 16*j mapping -> 64 lanes land on 32 distinct banks (2-way, free)
      {
        const int kp = t >> 4;   // 0..15 -> k rows 2kp, 2kp+1
        const int pg = t & 15;
        const float* xr0 = Xbase + (size_t)(k0 + 2 * kp) * 2048;
        const float* xr1 = xr0 + 2048;
#pragma unroll
        for (int j = 0; j < 4; j++) {
          int p = pg + 16 * j;
          unsigned pack = (unsigned)f2bf(xr0[p]) | ((unsigned)f2bf(xr1[p]) << 16);
          *(unsigned*)&sB[p * LDB + 2 * kp] = pack;
        }
      }
    }
    __syncthreads();

    // ---------- MFMA compute: wave wid owns m in [wid*64, wid*64+64) ----------
    {
      const int row = lane & 15;
      const int koff = (lane >> 4) * 8;  // k element offset within tile
      v8bf bfrag[4];
#pragma unroll
      for (int pt = 0; pt < 4; ++pt)
        bfrag[pt] = __builtin_bit_cast(v8bf, *(const v8u16*)&sB[(pt * 16 + row) * LDB + koff]);
#pragma unroll
      for (int mt = 0; mt < 4; ++mt) {
        v8bf afrag = __builtin_bit_cast(
            v8bf, *(const v8u16*)&sA[(wid * 64 + mt * 16 + row) * LDA + koff]);
#pragma unroll
        for (int pt = 0; pt < 4; ++pt)
          acc[mt][pt] = __builtin_amdgcn_mfma_f32_16x16x32_bf16(afrag, bfrag[pt],
                                                                acc[mt][pt], 0, 0, 0);
      }
    }
    __syncthreads();
  }

  // ---- epilogue: scale by exp(dA[m]) and store ----
  // C/D layout: col = lane&15, row = (lane>>4)*4 + reg
  float* Obase = outp + ((size_t)(b * 4096 + c * 256) * 32 + h) * 64;
  const int col = lane & 15;
  const int rbase = (lane >> 4) * 4;
#pragma unroll
  for (int mt = 0; mt < 4; ++mt) {
#pragma unroll
    for (int r = 0; r < 4; ++r) {
      int m = wid * 64 + mt * 16 + rbase + r;
      float e = s_edm[m];
      float* orow = Obase + (size_t)m * 2048;
#pragma unroll
      for (int pt = 0; pt < 4; ++pt)
        orow[pt * 16 + col] = acc[mt][pt][r] * e;
    }
  }
}

extern "C" void kernel_launch(void* const* d_in, const int* in_sizes, int n_in,
                              void* d_out, int out_size, void* d_ws, size_t ws_size,
                              hipStream_t stream) {
  const float* cb = (const float*)d_in[0];
  const float* x = (const float*)d_in[1];
  const float* dt = (const float*)d_in[2];
  const float* dA = (const float*)d_in[3];
  const float* C = (const float*)d_in[4];
  const float* pv = (const float*)d_in[5];
  const float* D = (const float*)d_in[6];
  float* out = (float*)d_out;
  // grid: h fastest so the 32 h-blocks sharing cb/C tiles are co-scheduled (L2/L3 reuse)
  mamba_cs_kernel<<<dim3(1024), dim3(256), 0, stream>>>(cb, x, dt, dA, C, pv, D, out);
}